// Round 1
// baseline (167.762 us; speedup 1.0000x reference)
//
#include <hip/hip_runtime.h>
#include <stdint.h>
#include <math.h>

#define D 2048
#define E 64
#define BM 32
#define BK 64
#define NCHUNK (D / BK)   // 32
#define NBLOCK 512        // 16384 rows / BM

typedef const __attribute__((address_space(1))) unsigned int guint;
typedef __attribute__((address_space(3))) unsigned int luint;

__device__ __forceinline__ void gl_lds16(const float* g, float* l) {
    __builtin_amdgcn_global_load_lds((guint*)g, (luint*)l, 16, 0, 0);
}

__global__ __launch_bounds__(256, 2)
void router_kernel(const float* __restrict__ x, const float* __restrict__ Wr,
                   float* __restrict__ out) {
    __shared__ float XS[2][BM * BK];   // x tile, row-major [row][k], linear
    __shared__ float WS[2][E * BK];    // W chunk, [e][k] with k ^= (e&7)<<2 swizzle

    const int tid  = threadIdx.x;
    const int lane = tid & 63;
    const int w    = tid >> 6;             // wave 0..3
    const int row0 = blockIdx.x * BM;

    // ---- staging address precompute ----
    // XS: wave w stages its own 8 rows as 2x 1024B loads.
    //   load i (0..1): row = w*8 + i*4 + (lane>>4), col = (lane&15)*4
    //   lds float off = w*512 + i*256 + lane*4  (== row*64 + col)
    const int xs_row = w * 8 + (lane >> 4);
    const int xs_col = (lane & 15) * 4;
    const float* xg0 = x + (size_t)(row0 + xs_row) * D + xs_col;
    float* const xs_l0 = &XS[0][w * 512 + lane * 4];
    float* const xs_l1 = &XS[1][w * 512 + lane * 4];

    // WS: 16 loads total, 4 per wave. load i (0..3):
    //   e = w*16 + i*4 + (lane>>4); stored k-word = ((lane&15)*4) ^ ((e&7)<<2)
    //   (pre-swizzled global source; LDS dest stays linear: w*1024 + i*256 + lane*4)
    int ws_e[4]; int ws_kw[4];
#pragma unroll
    for (int i = 0; i < 4; ++i) {
        ws_e[i]  = w * 16 + i * 4 + (lane >> 4);
        ws_kw[i] = ((lane & 15) * 4) ^ ((ws_e[i] & 7) << 2);
    }

#define STAGE(buf, k0) do {                                                     \
        gl_lds16(xg0 + (k0),           (buf) ? xs_l1 : xs_l0);                  \
        gl_lds16(xg0 + (k0) + 4 * D,   ((buf) ? xs_l1 : xs_l0) + 256);          \
        _Pragma("unroll")                                                       \
        for (int i = 0; i < 4; ++i) {                                           \
            gl_lds16(Wr + (size_t)ws_e[i] * D + (k0) + ws_kw[i],                \
                     &WS[buf][w * 1024 + i * 256 + lane * 4]);                  \
        }                                                                       \
    } while (0)

    float acc[8];
#pragma unroll
    for (int r = 0; r < 8; ++r) acc[r] = 0.0f;

    STAGE(0, 0);
    asm volatile("s_waitcnt vmcnt(0)" ::: "memory");
    __syncthreads();

    int cur = 0;
    for (int c = 0; c < NCHUNK; ++c) {
        if (c + 1 < NCHUNK) {
            const int k0n = (c + 1) * BK;
            STAGE(cur ^ 1, k0n);
        }
        const float* xs = &XS[cur][w * 512];   // this wave's 8 rows x 64 k
        const float* ws = &WS[cur][lane * 64]; // this lane's expert row (swizzled)
        const int ksw = (lane & 7) << 2;
#pragma unroll
        for (int kc = 0; kc < 16; ++kc) {
            const int k = kc * 4;
            const float4 wv = *(const float4*)(ws + (k ^ ksw));
#pragma unroll
            for (int r = 0; r < 8; ++r) {
                const float4 xv = *(const float4*)(xs + r * 64 + k); // uniform: LDS broadcast
                acc[r] = fmaf(xv.x, wv.x, acc[r]);
                acc[r] = fmaf(xv.y, wv.y, acc[r]);
                acc[r] = fmaf(xv.z, wv.z, acc[r]);
                acc[r] = fmaf(xv.w, wv.w, acc[r]);
            }
        }
        __syncthreads();
        cur ^= 1;
    }

    // ---- epilogue: softmax + top-2 per row (cross-lane over 64 experts) ----
    float* const out_gw    = out;               // [16384][2]
    float* const out_idx   = out + 32768;       // [16384][2] (indices as floats)
    float* const out_probs = out + 65536;       // [16384][64]

#pragma unroll 1
    for (int r = 0; r < 8; ++r) {
        const int row = row0 + w * 8 + r;
        const float v = acc[r];

        // wave max
        float m = v;
#pragma unroll
        for (int off = 32; off; off >>= 1) m = fmaxf(m, __shfl_xor(m, off));
        const float p = __expf(v - m);
        // wave sum
        float s = p;
#pragma unroll
        for (int off = 32; off; off >>= 1) s += __shfl_xor(s, off);
        const float inv_s = 1.0f / s;

        out_probs[(size_t)row * 64 + lane] = p * inv_s;

        // top-1 (ties -> lower index, matching lax.top_k)
        float v1 = v; int i1 = lane;
#pragma unroll
        for (int off = 32; off; off >>= 1) {
            const float ov = __shfl_xor(v1, off);
            const int   oi = __shfl_xor(i1, off);
            if (ov > v1 || (ov == v1 && oi < i1)) { v1 = ov; i1 = oi; }
        }
        // top-2: mask out winner
        float v2 = (lane == i1) ? -INFINITY : v; int i2 = lane;
#pragma unroll
        for (int off = 32; off; off >>= 1) {
            const float ov = __shfl_xor(v2, off);
            const int   oi = __shfl_xor(i2, off);
            if (ov > v2 || (ov == v2 && oi < i2)) { v2 = ov; i2 = oi; }
        }

        if (lane == 0) {
            const float p1 = __expf(v1 - m) * inv_s;
            const float p2 = __expf(v2 - m) * inv_s;
            const float inv12 = 1.0f / (p1 + p2);
            out_gw[(size_t)row * 2 + 0]  = p1 * inv12;
            out_gw[(size_t)row * 2 + 1]  = p2 * inv12;
            out_idx[(size_t)row * 2 + 0] = (float)i1;
            out_idx[(size_t)row * 2 + 1] = (float)i2;
        }
    }
#undef STAGE
}

extern "C" void kernel_launch(void* const* d_in, const int* in_sizes, int n_in,
                              void* d_out, int out_size, void* d_ws, size_t ws_size,
                              hipStream_t stream) {
    const float* x  = (const float*)d_in[0];
    const float* Wr = (const float*)d_in[1];
    float* out = (float*)d_out;
    hipLaunchKernelGGL(router_kernel, dim3(NBLOCK), dim3(256), 0, stream, x, Wr, out);
}